// Round 6
// baseline (6149.775 us; speedup 1.0000x reference)
//
#include <hip/hip_runtime.h>
#include <hip/hip_bf16.h>

#define NB 32      // batch
#define NS 256     // seq len
#define NI 1024    // input size
#define NO 1024    // hidden size
#define NK 2048    // NI + NO
#define NC 4096    // 4 * NO
#define LN_EPS 1e-5f
#define SPIN_GUARD (1 << 18)

// padded layouts (anti cache-line-serialization at the coherent point; r4-proven)
#define SROW_STRIDE 16   // floats per row slot = 64B; s at +0, ss at +8 (32B sector)
#define CNT_STRIDE  32   // u32 per step slot = 128B

typedef __attribute__((ext_vector_type(4))) float f32x4;
typedef __attribute__((ext_vector_type(4))) unsigned int u32x4;

__device__ __forceinline__ f32x4 mfma_bf16_16x16x32(u32x4 a, u32x4 b, f32x4 c) {
  asm volatile("v_mfma_f32_16x16x32_bf16 %0, %1, %2, %0" : "+v"(c) : "v"(a), "v"(b));
  return c;
}

__device__ __forceinline__ float sigf(float x) { return 1.0f / (1.0f + __expf(-x)); }
// tanh(x) = 1 - 2/(e^{2x}+1); exp overflow -> inf -> 1, underflow -> 0 -> -1. Both correct.
__device__ __forceinline__ float tanhfast(float x) {
  return 1.0f - 2.0f / (__expf(2.0f * x) + 1.0f);
}

// ---- MALL-coherent primitives (round-3/4 proven recipe) ----
__device__ __forceinline__ unsigned int load_coh_u32(const void* p) {
  unsigned int v;
  asm volatile("global_load_dword %0, %1, off sc0 sc1\n\ts_waitcnt vmcnt(0)"
               : "=&v"(v) : "v"(p));
  return v;
}
#define COH_LOAD2_F32(d0, d1, a0, a1)                                   \
  asm volatile("global_load_dword %0, %2, off sc0 sc1\n\t"              \
               "global_load_dword %1, %3, off sc0 sc1\n\t"              \
               "s_waitcnt vmcnt(0)"                                     \
               : "=&v"(d0), "=&v"(d1) : "v"(a0), "v"(a1))
__device__ __forceinline__ void atomic_add_coh_u32(void* p, unsigned int v) {
  asm volatile("global_atomic_add %0, %1, off sc1" :: "v"(p), "v"(v) : "memory");
}
__device__ __forceinline__ void atomic_add_coh_f32(void* p, float v) {
  asm volatile("global_atomic_add_f32 %0, %1, off sc1" :: "v"(p), "v"(v) : "memory");
}
__device__ __forceinline__ void poll_coh_ge(const unsigned int* p, unsigned int target) {
  for (int g = 0; g < SPIN_GUARD; ++g) {
    if (load_coh_u32(p) >= target) return;
    __builtin_amdgcn_s_sleep(2);
  }
}

// ---------------- setup kernels (round-0 proven) ----------------

// x fp32 [m][t][k] -> xfrag bf16 in MFMA A-fragment order.
__global__ void pack_x(const float* __restrict__ x, __hip_bfloat16* __restrict__ xfrag) {
  const int t = blockIdx.x, kt = blockIdx.y;
  const int tid = threadIdx.x;
  const int plane = tid >> 6, l = tid & 63, q = (l >> 4), ln = l & 15;
  const int m = plane * 16 + ln;
  const float* src = x + ((size_t)m * NS + t) * NI + kt * 32 + q * 8;
  float4 v0 = *(const float4*)src;
  float4 v1 = *(const float4*)(src + 4);
  __align__(16) __hip_bfloat16 tmp[8];
  tmp[0] = __float2bfloat16(v0.x); tmp[1] = __float2bfloat16(v0.y);
  tmp[2] = __float2bfloat16(v0.z); tmp[3] = __float2bfloat16(v0.w);
  tmp[4] = __float2bfloat16(v1.x); tmp[5] = __float2bfloat16(v1.y);
  tmp[6] = __float2bfloat16(v1.z); tmp[7] = __float2bfloat16(v1.w);
  *(u32x4*)(xfrag + (((size_t)t * 32 + kt) * 2 + plane) * 512 + l * 8) = *(const u32x4*)tmp;
}

// W fp32 [k=2048][n=4096] -> WF bf16 in MFMA-fragment order.
__global__ void pack_wf(const float* __restrict__ W, __hip_bfloat16* __restrict__ WF) {
  const int blk = blockIdx.x;
  const int b = blk >> 6, kt = blk & 63;
  const int l = threadIdx.x, q = l >> 4, c = l & 15;
  const int n  = ((c >> 2) << 10) + b * 4 + (c & 3);
  const int k0 = kt * 32 + q * 8;
  __align__(16) __hip_bfloat16 tmp[8];
#pragma unroll
  for (int j = 0; j < 8; ++j)
    tmp[j] = __float2bfloat16(W[(size_t)(k0 + j) * NC + n]);
  *(u32x4*)(WF + ((size_t)(b * 64 + kt) * 64 + l) * 8) = *(const u32x4*)tmp;
}

// hfrag index for h[m][j] (A-fragment order, 2 planes of 16 rows):
__device__ __forceinline__ size_t hfrag_idx(int m, int j) {
  const int kt = j >> 5, q = (j >> 3) & 3, jj = j & 7;
  const int plane = m >> 4, l = q * 16 + (m & 15);
  return (((size_t)kt * 2 + plane) * 64 + l) * 8 + jj;
}

// init h (fragment order + fp32) and c from init_hx/init_cx (broadcast row 0)
__global__ void init_state(const float* __restrict__ hx0, const float* __restrict__ cx0,
                           __hip_bfloat16* __restrict__ hfrag, float* __restrict__ cst,
                           float* __restrict__ hf) {
  const int i = blockIdx.x * 256 + threadIdx.x;  // 32768 = NB*NO
  const int m = i >> 10, j = i & (NO - 1);
  const float hv = hx0[j];
  hfrag[hfrag_idx(m, j)] = __float2bfloat16(hv);
  hf[i]  = hv;
  cst[i] = cx0[j];
}

// ---------------- hoisted x-GEMM (round-5 proven) ----------------
__global__ __launch_bounds__(512)
void xgemm_all(const __hip_bfloat16* __restrict__ xfrag,
               const __hip_bfloat16* __restrict__ WF,
               const float* __restrict__ bias,
               __hip_bfloat16* __restrict__ xa) {
  __shared__ __align__(16) float xch[8 * 2 * 256];   // 16KB partials
  const int b = blockIdx.x, tid = threadIdx.x;
  const int wv = tid >> 6, l = tid & 63;
  const int kt0 = wv * 4;                 // x k-tiles 0..31, 4 per wave
  u32x4 bb[4];
  {
    const __hip_bfloat16* bp = WF + ((size_t)(b * 64 + kt0) * 64 + l) * 8;
#pragma unroll
    for (int i = 0; i < 4; ++i) bb[i] = *(const u32x4*)(bp + (size_t)i * 512);
  }
  const int row = tid >> 4, c = tid & 15;
  const int p = row >> 4, rr = row & 15;
  const int idx = ((rr >> 2) * 16 + c) * 4 + (rr & 3);
  const int n = ((c >> 2) << 10) + b * 4 + (c & 3);
  const float bn = bias[n];

  for (int t = 0; t < NS; ++t) {
    f32x4 acc0 = {0.f, 0.f, 0.f, 0.f}, acc1 = {0.f, 0.f, 0.f, 0.f};
    asm volatile("s_nop 1" ::);  // VALU-write(acc init) -> MFMA-read-C hazard
    const __hip_bfloat16* ap = xfrag + ((size_t)t * 32 + kt0) * 1024 + l * 8;
#pragma unroll
    for (int i = 0; i < 4; ++i) {
      u32x4 a0 = *(const u32x4*)(ap + (size_t)i * 1024);        // plane 0
      u32x4 a1 = *(const u32x4*)(ap + (size_t)i * 1024 + 512);  // plane 1
      acc0 = mfma_bf16_16x16x32(a0, bb[i], acc0);
      acc1 = mfma_bf16_16x16x32(a1, bb[i], acc1);
    }
    asm volatile("s_nop 7\n\ts_nop 7" ::);  // MFMA-write -> VALU-read hazard
    *(f32x4*)(xch + (wv * 2 + 0) * 256 + l * 4) = acc0;
    *(f32x4*)(xch + (wv * 2 + 1) * 256 + l * 4) = acc1;
    __syncthreads();
    float v = bn;
#pragma unroll
    for (int w = 0; w < 8; ++w) v += xch[(w * 2 + p) * 256 + idx];
    xa[((size_t)t * 256 + b) * 512 + tid] = __float2bfloat16(v);
    __syncthreads();   // xch reuse next t
  }
}

// ---------------- fused per-step kernel (tier1): GEMM + LN + gates ----------------
// ONE dispatch per step. 256 blocks x 512 thr (1 block/CU, co-resident by
// capacity: 512 thr, 18KB LDS, modest VGPR). Block b owns cols
// n(c)=(c>>2)*1024+b*4+(c&3) => all 4 gate pre-activations of hidden units
// j=4b..4b+3 are block-local. Only the 32x2 LN stats cross blocks, via the
// round-3/4-proven sc1-atomic + padded-slot + bypass-load rendezvous.
// h(t) is read from hfrag (published by the PREVIOUS dispatch -> kernel
// boundary provides coherence; no flags needed for h). h(t+1) written with
// plain stores at the end.
__global__ __launch_bounds__(512)
void step_fused(__hip_bfloat16* hfrag,                       // in: h(t)  out: h(t+1)
                const __hip_bfloat16* __restrict__ WF,
                const __hip_bfloat16* __restrict__ xa,
                const float* __restrict__ gamma,
                const float* __restrict__ beta,
                float* __restrict__ cst,
                float* __restrict__ out,
                float* __restrict__ srow_t,                  // [32][SROW_STRIDE] for this t
                unsigned int* __restrict__ scnt_t,           // 1 padded slot for this t
                int t) {
  __shared__ __align__(16) float xch[8 * 2 * 256];   // 16KB GEMM partials
  __shared__ __align__(16) float combB[32 * 16];     // 2KB block-local comb
  const int b = blockIdx.x, tid = threadIdx.x;
  const int wv = tid >> 6, l = tid & 63;

  // ---- h-GEMM: K=1024 = 32 k-tiles, 4 per wave (round-5 proven structure) ----
  const int kt0 = wv * 4;
  const __hip_bfloat16* ap = hfrag + (size_t)kt0 * 1024 + l * 8;
  const __hip_bfloat16* bp = WF + ((size_t)(b * 64 + 32 + kt0) * 64 + l) * 8;
  // xa seed (independent load; scheduler hoists it over the MFMA loop)
  const float xav = __bfloat162float(xa[((size_t)t * 256 + b) * 512 + tid]);

  f32x4 acc0 = {0.f, 0.f, 0.f, 0.f}, acc1 = {0.f, 0.f, 0.f, 0.f};
  asm volatile("s_nop 1" ::);  // VALU-write(acc init) -> MFMA-read-C hazard
#pragma unroll
  for (int i = 0; i < 4; ++i) {
    u32x4 a0 = *(const u32x4*)(ap + (size_t)i * 1024);        // plane 0
    u32x4 a1 = *(const u32x4*)(ap + (size_t)i * 1024 + 512);  // plane 1
    u32x4 bbv = *(const u32x4*)(bp + (size_t)i * 512);
    acc0 = mfma_bf16_16x16x32(a0, bbv, acc0);
    acc1 = mfma_bf16_16x16x32(a1, bbv, acc1);
  }
  asm volatile("s_nop 7\n\ts_nop 7" ::);  // MFMA-write -> VALU-read hazard

  *(f32x4*)(xch + (wv * 2 + 0) * 256 + l * 4) = acc0;
  *(f32x4*)(xch + (wv * 2 + 1) * 256 + l * 4) = acc1;
  __syncthreads();

  // ---- epilogue: comb value, block-local store, LN partial stats ----
  const int row = tid >> 4, c = tid & 15;
  {
    const int p = row >> 4, rr = row & 15;
    const int idx = ((rr >> 2) * 16 + c) * 4 + (rr & 3);
    float v = xav;
#pragma unroll
    for (int w = 0; w < 8; ++w) v += xch[(w * 2 + p) * 256 + idx];
    combB[row * 16 + c] = v;
    float s = v, ss = v * v;
#pragma unroll
    for (int off = 1; off < 16; off <<= 1) {
      s  += __shfl_xor(s, off);
      ss += __shfl_xor(ss, off);
    }
    if (c == 0) {
      float* slot = srow_t + row * SROW_STRIDE;
      atomic_add_coh_f32(slot + 0, s);
      atomic_add_coh_f32(slot + 8, ss);   // +32B: own sector
    }
  }
  // drain inline-asm atomics, then barrier => this block's adds are at MALL
  asm volatile("s_waitcnt vmcnt(0)" ::: "memory");
  __syncthreads();
  if (tid == 0) {
    atomic_add_coh_u32(scnt_t, 1u);
    poll_coh_ge(scnt_t, 256u);   // single-lane poll; rest of block parks at barrier
  }
  __syncthreads();

  // ---- gate phase (wave 0): lane l -> (m=l>>1, half=l&1), units j0, j0+1 ----
  if (wv == 0) {
    const int gm = l >> 1, gh = l & 1;
    const int j0 = b * 4 + 2 * gh;
    const float* slot = srow_t + gm * SROW_STRIDE;
    float sv, ssv;
    COH_LOAD2_F32(sv, ssv, slot + 0, slot + 8);
    const float mean = sv * (1.f / NC);
    const float var  = ssv * (1.f / NC) - mean * mean;
    const float rs = rsqrtf(var + LN_EPS);
    const int cb = 2 * gh;
    float pre[4][2];
#pragma unroll
    for (int g = 0; g < 4; ++g) {
      const float ga0 = gamma[g * NO + j0], ga1 = gamma[g * NO + j0 + 1];
      const float be0 = beta[g * NO + j0],  be1 = beta[g * NO + j0 + 1];
      pre[g][0] = (combB[gm * 16 + g * 4 + cb]     - mean) * rs * ga0 + be0;
      pre[g][1] = (combB[gm * 16 + g * 4 + cb + 1] - mean) * rs * ga1 + be1;
    }
    float2 cold = *(const float2*)(cst + (size_t)gm * NO + j0);
    const float cc0 = sigf(pre[1][0]) * cold.x + sigf(pre[0][0]) * tanhfast(pre[2][0]);
    const float cc1 = sigf(pre[1][1]) * cold.y + sigf(pre[0][1]) * tanhfast(pre[2][1]);
    const float hh0 = sigf(pre[3][0]) * cc0;
    const float hh1 = sigf(pre[3][1]) * cc1;
    float2 cnew; cnew.x = cc0; cnew.y = cc1;
    *(float2*)(cst + (size_t)gm * NO + j0) = cnew;
    float2 o2; o2.x = hh0; o2.y = hh1;
    *(float2*)(out + ((size_t)gm * NS + t) * NO + j0) = o2;
    __hip_bfloat16 hb0 = __float2bfloat16(hh0), hb1 = __float2bfloat16(hh1);
    unsigned int hp = (unsigned int)*(unsigned short*)&hb0 |
                      ((unsigned int)*(unsigned short*)&hb1 << 16);
    // plain store: next dispatch's reads are ordered by the kernel boundary.
    // j0 even -> jj in {0,2,4,6} -> 4B-aligned element pair.
    *(unsigned int*)(hfrag + hfrag_idx(gm, j0)) = hp;
  }
}

// ---------------- tier2 per-step kernels (round-0 proven, unchanged) ----------------
__global__ __launch_bounds__(512)
void step_gemm_mfma(const __hip_bfloat16* __restrict__ xfrag,
                    const __hip_bfloat16* __restrict__ hfrag,
                    const __hip_bfloat16* __restrict__ WF,
                    const float* __restrict__ bias,
                    float* __restrict__ comb, int t) {
  __shared__ __align__(16) float xch[8 * 2 * 256];   // 16KB
  const int b = blockIdx.x, tid = threadIdx.x;
  const int wv = tid >> 6, l = tid & 63;

  const __hip_bfloat16* ap = (wv < 4)
      ? xfrag + ((size_t)t * 32 + wv * 8) * 1024 + l * 8
      : hfrag + ((size_t)(wv - 4) * 8) * 1024 + l * 8;
  const __hip_bfloat16* bp = WF + ((size_t)(b * 64 + wv * 8) * 64 + l) * 8;

  f32x4 acc0 = {0.f, 0.f, 0.f, 0.f}, acc1 = {0.f, 0.f, 0.f, 0.f};
  asm volatile("s_nop 1" ::);
#pragma unroll
  for (int i = 0; i < 8; ++i) {
    u32x4 a0 = *(const u32x4*)(ap + (size_t)i * 1024);
    u32x4 a1 = *(const u32x4*)(ap + (size_t)i * 1024 + 512);
    u32x4 bb = *(const u32x4*)(bp + (size_t)i * 512);
    acc0 = mfma_bf16_16x16x32(a0, bb, acc0);
    acc1 = mfma_bf16_16x16x32(a1, bb, acc1);
  }
  asm volatile("s_nop 7\n\ts_nop 7" ::);

  *(f32x4*)(xch + (wv * 2 + 0) * 256 + l * 4) = acc0;
  *(f32x4*)(xch + (wv * 2 + 1) * 256 + l * 4) = acc1;
  __syncthreads();

  const int row = tid >> 4, c = tid & 15;
  const int p = row >> 4, rr = row & 15;
  const int idx = ((rr >> 2) * 16 + c) * 4 + (rr & 3);
  const int n = ((c >> 2) << 10) + b * 4 + (c & 3);
  float v = bias[n];
#pragma unroll
  for (int w = 0; w < 8; ++w) v += xch[(w * 2 + p) * 256 + idx];
  comb[(size_t)row * NC + n] = v;
}

__global__ __launch_bounds__(1024)
void step_update_row(const float* __restrict__ comb,
                     const float* __restrict__ gamma,
                     const float* __restrict__ beta,
                     float* __restrict__ cst,
                     float* __restrict__ out,
                     __hip_bfloat16* __restrict__ hfrag,
                     int t) {
  __shared__ __align__(16) float combL[NC];
  __shared__ float red[16][2];
  __shared__ float stat[2];
  const int m = blockIdx.x, tid = threadIdx.x;

  f32x4 cv = *(const f32x4*)(comb + (size_t)m * NC + tid * 4);
  *(f32x4*)(combL + tid * 4) = cv;
  float s  = cv[0] + cv[1] + cv[2] + cv[3];
  float ss = cv[0] * cv[0] + cv[1] * cv[1] + cv[2] * cv[2] + cv[3] * cv[3];
#pragma unroll
  for (int off = 1; off < 64; off <<= 1) {
    s  += __shfl_xor(s, off);
    ss += __shfl_xor(ss, off);
  }
  const int wid = tid >> 6;
  if ((tid & 63) == 0) { red[wid][0] = s; red[wid][1] = ss; }
  __syncthreads();
  if (tid == 0) {
    float s2 = 0.f, ss2 = 0.f;
#pragma unroll
    for (int i = 0; i < 16; ++i) { s2 += red[i][0]; ss2 += red[i][1]; }
    const float mean = s2 * (1.f / NC);
    const float var  = ss2 * (1.f / NC) - mean * mean;
    stat[0] = mean;
    stat[1] = rsqrtf(var + LN_EPS);
  }
  __syncthreads();
  const float mean = stat[0], rs = stat[1];
  const int j = tid;
  const float iv = (combL[j]          - mean) * rs * gamma[j]          + beta[j];
  const float fv = (combL[NO + j]     - mean) * rs * gamma[NO + j]     + beta[NO + j];
  const float gv = (combL[2 * NO + j] - mean) * rs * gamma[2 * NO + j] + beta[2 * NO + j];
  const float ov = (combL[3 * NO + j] - mean) * rs * gamma[3 * NO + j] + beta[3 * NO + j];
  const float cold = cst[(size_t)m * NO + j];
  const float cc = sigf(fv) * cold + sigf(iv) * tanhfast(gv);
  const float hh = sigf(ov) * cc;
  cst[(size_t)m * NO + j] = cc;
  out[((size_t)m * NS + t) * NO + j] = hh;
  hfrag[hfrag_idx(m, j)] = __float2bfloat16(hh);
}

// ---------------- fallback (small ws): fp32 path ----------------

__launch_bounds__(256)
__global__ void step_gemm_f32(const float* __restrict__ x, const float* __restrict__ hf,
                              const float* __restrict__ W, const float* __restrict__ bias,
                              float* __restrict__ comb, int t) {
  const int blk = blockIdx.x;
  const int tid = threadIdx.x;
  const int n   = blk * 16 + (tid & 15);
  const int mlo = tid >> 4;
  float a0 = 0.f, a1 = 0.f;
  for (int k = 0; k < NI; ++k) {
    const float wv = W[(size_t)k * NC + n];
    a0 += x[((size_t)mlo * NS + t) * NI + k] * wv;
    a1 += x[((size_t)(mlo + 16) * NS + t) * NI + k] * wv;
  }
  for (int k = 0; k < NO; ++k) {
    const float wv = W[(size_t)(NI + k) * NC + n];
    a0 += hf[mlo * NO + k] * wv;
    a1 += hf[(mlo + 16) * NO + k] * wv;
  }
  comb[(size_t)mlo * NC + n] = a0 + bias[n];
  comb[(size_t)(mlo + 16) * NC + n] = a1 + bias[n];
}

__global__ __launch_bounds__(1024)
void step_update_row_f32(const float* __restrict__ comb,
                         const float* __restrict__ gamma,
                         const float* __restrict__ beta,
                         float* __restrict__ cst,
                         float* __restrict__ out,
                         float* __restrict__ hf,
                         int t) {
  __shared__ __align__(16) float combL[NC];
  __shared__ float red[16][2];
  __shared__ float stat[2];
  const int m = blockIdx.x, tid = threadIdx.x;
  f32x4 cv = *(const f32x4*)(comb + (size_t)m * NC + tid * 4);
  *(f32x4*)(combL + tid * 4) = cv;
  float s  = cv[0] + cv[1] + cv[2] + cv[3];
  float ss = cv[0] * cv[0] + cv[1] * cv[1] + cv[2] * cv[2] + cv[3] * cv[3];
#pragma unroll
  for (int off = 1; off < 64; off <<= 1) {
    s  += __shfl_xor(s, off);
    ss += __shfl_xor(ss, off);
  }
  const int wid = tid >> 6;
  if ((tid & 63) == 0) { red[wid][0] = s; red[wid][1] = ss; }
  __syncthreads();
  if (tid == 0) {
    float s2 = 0.f, ss2 = 0.f;
    for (int i = 0; i < 16; ++i) { s2 += red[i][0]; ss2 += red[i][1]; }
    const float mean = s2 * (1.f / NC);
    const float var  = ss2 * (1.f / NC) - mean * mean;
    stat[0] = mean;
    stat[1] = rsqrtf(var + LN_EPS);
  }
  __syncthreads();
  const float mean = stat[0], rs = stat[1];
  const int j = tid;
  const float iv = (combL[j]          - mean) * rs * gamma[j]          + beta[j];
  const float fv = (combL[NO + j]     - mean) * rs * gamma[NO + j]     + beta[NO + j];
  const float gv = (combL[2 * NO + j] - mean) * rs * gamma[2 * NO + j] + beta[2 * NO + j];
  const float ov = (combL[3 * NO + j] - mean) * rs * gamma[3 * NO + j] + beta[3 * NO + j];
  const float cold = cst[(size_t)m * NO + j];
  const float cc = sigf(fv) * cold + sigf(iv) * tanhfast(gv);
  const float hh = sigf(ov) * cc;
  cst[(size_t)m * NO + j] = cc;
  out[((size_t)m * NS + t) * NO + j] = hh;
  hf[(size_t)m * NO + j] = hh;
}

// ---------------- launch ----------------

extern "C" void kernel_launch(void* const* d_in, const int* in_sizes, int n_in,
                              void* d_out, int out_size, void* d_ws, size_t ws_size,
                              hipStream_t stream) {
  (void)in_sizes; (void)n_in; (void)out_size;
  const float* x     = (const float*)d_in[0];
  const float* W     = (const float*)d_in[1];
  const float* bias  = (const float*)d_in[2];
  const float* gamma = (const float*)d_in[3];
  const float* beta  = (const float*)d_in[4];
  const float* hx0   = (const float*)d_in[5];
  const float* cx0   = (const float*)d_in[6];
  float* outp = (float*)d_out;

  char* ws = (char*)d_ws;
  size_t off = 0;
  auto alloc = [&](size_t bytes) -> char* {
    off = (off + 255) & ~(size_t)255;
    char* p = ws + off;
    off += bytes;
    return p;
  };
  // small buffers first (fallback needs only comb/cst/hf)
  float* comb           = (float*)alloc((size_t)NB * NC * 4);            // 512KB
  float* cst            = (float*)alloc((size_t)NB * NO * 4);            // 128KB
  float* hf             = (float*)alloc((size_t)NB * NO * 4);            // 128KB
  __hip_bfloat16* hfrag = (__hip_bfloat16*)alloc((size_t)NB * NO * 2);   // 64KB
  float* srow           = (float*)alloc((size_t)NS * 32 * SROW_STRIDE * 4);   // 512KB
  unsigned int* scnt    = (unsigned int*)alloc((size_t)NS * CNT_STRIDE * 4);  // 32KB
  // mid buffers (tier2 = exact round-0 path)
  __hip_bfloat16* xfrag = (__hip_bfloat16*)alloc((size_t)NB * NS * NI * 2);  // 16.8MB
  __hip_bfloat16* WF    = (__hip_bfloat16*)alloc((size_t)NK * NC * 2);       // 16.8MB
  const size_t off_tier2 = off;
  // big buffer (tier1 = hoisted-x + fused path): xa bf16 [t][block][tid]
  __hip_bfloat16* xa    = (__hip_bfloat16*)alloc((size_t)NS * NB * NC * 2);  // 67MB
  const size_t off_tier1 = off;

  const bool tier1 = (ws_size >= off_tier1);  // ws_size constant -> same path every call
  const bool tier2 = (ws_size >= off_tier2);

  if (tier1) {
    hipMemsetAsync(srow, 0, (size_t)NS * 32 * SROW_STRIDE * 4, stream);
    hipMemsetAsync(scnt, 0, (size_t)NS * CNT_STRIDE * 4, stream);
    hipLaunchKernelGGL(init_state, dim3((NB * NO) / 256), dim3(256), 0, stream,
                       hx0, cx0, hfrag, cst, hf);
    hipLaunchKernelGGL(pack_x, dim3(NS, 32), dim3(128), 0, stream, x, xfrag);
    hipLaunchKernelGGL(pack_wf, dim3(256 * 64), dim3(64), 0, stream, W, WF);
    hipLaunchKernelGGL(xgemm_all, dim3(256), dim3(512), 0, stream,
                       xfrag, WF, bias, xa);
    for (int t = 0; t < NS; ++t) {
      hipLaunchKernelGGL(step_fused, dim3(256), dim3(512), 0, stream,
                         hfrag, WF, xa, gamma, beta, cst, outp,
                         srow + (size_t)t * 32 * SROW_STRIDE,
                         scnt + (size_t)t * CNT_STRIDE, t);
    }
  } else if (tier2) {
    hipLaunchKernelGGL(init_state, dim3((NB * NO) / 256), dim3(256), 0, stream,
                       hx0, cx0, hfrag, cst, hf);
    hipLaunchKernelGGL(pack_x, dim3(NS, 32), dim3(128), 0, stream, x, xfrag);
    hipLaunchKernelGGL(pack_wf, dim3(256 * 64), dim3(64), 0, stream, W, WF);
    for (int t = 0; t < NS; ++t) {
      hipLaunchKernelGGL(step_gemm_mfma, dim3(256), dim3(512), 0, stream,
                         xfrag, hfrag, WF, bias, comb, t);
      hipLaunchKernelGGL(step_update_row, dim3(NB), dim3(1024), 0, stream,
                         comb, gamma, beta, cst, outp, hfrag, t);
    }
  } else {
    hipLaunchKernelGGL(init_state, dim3((NB * NO) / 256), dim3(256), 0, stream,
                       hx0, cx0, hfrag, cst, hf);
    for (int t = 0; t < NS; ++t) {
      hipLaunchKernelGGL(step_gemm_f32, dim3(256), dim3(256), 0, stream,
                         x, hf, W, bias, comb, t);
      hipLaunchKernelGGL(step_update_row_f32, dim3(NB), dim3(1024), 0, stream,
                         comb, gamma, beta, cst, outp, hf, t);
    }
  }
}

// Round 7
// 2448.610 us; speedup vs baseline: 2.5115x; 2.5115x over previous
//
#include <hip/hip_runtime.h>
#include <hip/hip_bf16.h>

#define NB 32      // batch
#define NS 256     // seq len
#define NI 1024    // input size
#define NO 1024    // hidden size
#define NK 2048    // NI + NO
#define NC 4096    // 4 * NO
#define LN_EPS 1e-5f

typedef __attribute__((ext_vector_type(4))) float f32x4;
typedef __attribute__((ext_vector_type(4))) unsigned int u32x4;

__device__ __forceinline__ f32x4 mfma_bf16_16x16x32(u32x4 a, u32x4 b, f32x4 c) {
  asm volatile("v_mfma_f32_16x16x32_bf16 %0, %1, %2, %0" : "+v"(c) : "v"(a), "v"(b));
  return c;
}

__device__ __forceinline__ float sigf(float x) { return 1.0f / (1.0f + __expf(-x)); }
// tanh(x) = 1 - 2/(e^{2x}+1); exp overflow -> inf -> 1, underflow -> 0 -> -1. Both correct.
__device__ __forceinline__ float tanhfast(float x) {
  return 1.0f - 2.0f / (__expf(2.0f * x) + 1.0f);
}

// ---------------- setup kernels ----------------

// x fp32 [m][t][k] -> xfrag bf16 in MFMA A-fragment order:
// xfrag[((t*32 + kt)*2 + plane)*512 + l*8 + j] = x[m=plane*16+(l&15)][t][kt*32+(l>>4)*8+j]
// grid (256 t, 32 kt) x 128 thr.
__global__ void pack_x(const float* __restrict__ x, __hip_bfloat16* __restrict__ xfrag) {
  const int t = blockIdx.x, kt = blockIdx.y;
  const int tid = threadIdx.x;
  const int plane = tid >> 6, l = tid & 63, q = (l >> 4), ln = l & 15;
  const int m = plane * 16 + ln;
  const float* src = x + ((size_t)m * NS + t) * NI + kt * 32 + q * 8;
  float4 v0 = *(const float4*)src;
  float4 v1 = *(const float4*)(src + 4);
  __align__(16) __hip_bfloat16 tmp[8];
  tmp[0] = __float2bfloat16(v0.x); tmp[1] = __float2bfloat16(v0.y);
  tmp[2] = __float2bfloat16(v0.z); tmp[3] = __float2bfloat16(v0.w);
  tmp[4] = __float2bfloat16(v1.x); tmp[5] = __float2bfloat16(v1.y);
  tmp[6] = __float2bfloat16(v1.z); tmp[7] = __float2bfloat16(v1.w);
  *(u32x4*)(xfrag + (((size_t)t * 32 + kt) * 2 + plane) * 512 + l * 8) = *(const u32x4*)tmp;
}

// W fp32 [k=2048][n=4096] -> WF bf16 in MFMA-fragment order (round-3 verified).
__global__ void pack_wf(const float* __restrict__ W, __hip_bfloat16* __restrict__ WF) {
  const int blk = blockIdx.x;
  const int b = blk >> 6, kt = blk & 63;
  const int l = threadIdx.x, q = l >> 4, c = l & 15;
  const int n  = ((c >> 2) << 10) + b * 4 + (c & 3);
  const int k0 = kt * 32 + q * 8;
  __align__(16) __hip_bfloat16 tmp[8];
#pragma unroll
  for (int j = 0; j < 8; ++j)
    tmp[j] = __float2bfloat16(W[(size_t)(k0 + j) * NC + n]);
  *(u32x4*)(WF + ((size_t)(b * 64 + kt) * 64 + l) * 8) = *(const u32x4*)tmp;
}

// hfrag index for h[m][j] (A-fragment order, 2 planes of 16 rows):
__device__ __forceinline__ size_t hfrag_idx(int m, int j) {
  const int kt = j >> 5, q = (j >> 3) & 3, jj = j & 7;
  const int plane = m >> 4, l = q * 16 + (m & 15);
  return (((size_t)kt * 2 + plane) * 64 + l) * 8 + jj;
}

// init h (fragment order + fp32) and c from init_hx/init_cx (broadcast row 0)
__global__ void init_state(const float* __restrict__ hx0, const float* __restrict__ cx0,
                           __hip_bfloat16* __restrict__ hfrag, float* __restrict__ cst,
                           float* __restrict__ hf) {
  const int i = blockIdx.x * 256 + threadIdx.x;  // 32768 = NB*NO
  const int m = i >> 10, j = i & (NO - 1);
  const float hv = hx0[j];
  hfrag[hfrag_idx(m, j)] = __float2bfloat16(hv);
  hf[i]  = hv;
  cst[i] = cx0[j];
}

// ---------------- per-step kernel A: MFMA GEMM ----------------
// grid 256 x 512 (8 waves, 2/SIMD). Block b owns 16 interleaved n-cols
// n(c) = (c>>2)*1024 + b*4 + (c&3). Wave wv covers K-tiles [wv*8, wv*8+8):
// waves 0..3 read xfrag (x part, K<1024), waves 4..7 read hfrag. All loads
// (A and B) are contiguous 16B/lane. K-partials reduced via 16KB LDS.
__global__ __launch_bounds__(512)
void step_gemm_mfma(const __hip_bfloat16* __restrict__ xfrag,
                    const __hip_bfloat16* __restrict__ hfrag,
                    const __hip_bfloat16* __restrict__ WF,
                    const float* __restrict__ bias,
                    float* __restrict__ comb, int t) {
  __shared__ __align__(16) float xch[8 * 2 * 256];   // 16KB
  const int b = blockIdx.x, tid = threadIdx.x;
  const int wv = tid >> 6, l = tid & 63;

  const __hip_bfloat16* ap = (wv < 4)
      ? xfrag + ((size_t)t * 32 + wv * 8) * 1024 + l * 8
      : hfrag + ((size_t)(wv - 4) * 8) * 1024 + l * 8;
  const __hip_bfloat16* bp = WF + ((size_t)(b * 64 + wv * 8) * 64 + l) * 8;

  f32x4 acc0 = {0.f, 0.f, 0.f, 0.f}, acc1 = {0.f, 0.f, 0.f, 0.f};
  asm volatile("s_nop 1" ::);  // VALU-write(acc init) -> MFMA-read-C hazard
#pragma unroll
  for (int i = 0; i < 8; ++i) {
    u32x4 a0 = *(const u32x4*)(ap + (size_t)i * 1024);        // plane 0 (rows 0..15)
    u32x4 a1 = *(const u32x4*)(ap + (size_t)i * 1024 + 512);  // plane 1 (rows 16..31)
    u32x4 bb = *(const u32x4*)(bp + (size_t)i * 512);
    acc0 = mfma_bf16_16x16x32(a0, bb, acc0);
    acc1 = mfma_bf16_16x16x32(a1, bb, acc1);
  }
  asm volatile("s_nop 7\n\ts_nop 7" ::);  // MFMA-write -> VALU-read hazard

  *(f32x4*)(xch + (wv * 2 + 0) * 256 + l * 4) = acc0;
  *(f32x4*)(xch + (wv * 2 + 1) * 256 + l * 4) = acc1;
  __syncthreads();

  // thread -> (row=tid>>4, c=tid&15); D layout: lane=(rr>>2)*16+c, reg=rr&3
  const int row = tid >> 4, c = tid & 15;
  const int p = row >> 4, rr = row & 15;
  const int idx = ((rr >> 2) * 16 + c) * 4 + (rr & 3);
  const int n = ((c >> 2) << 10) + b * 4 + (c & 3);
  float v = bias[n];
#pragma unroll
  for (int w = 0; w < 8; ++w) v += xch[(w * 2 + p) * 256 + idx];
  comb[(size_t)row * NC + n] = v;
}

// ---------------- per-step kernel B: LN + gates + state ----------------
// grid 32 x 1024. Block = batch row m. Block-local LN stats, gates, c/h
// update; writes h in fragment order for next step's GEMM.
__global__ __launch_bounds__(1024)
void step_update_row(const float* __restrict__ comb,
                     const float* __restrict__ gamma,
                     const float* __restrict__ beta,
                     float* __restrict__ cst,
                     float* __restrict__ out,
                     __hip_bfloat16* __restrict__ hfrag,
                     int t) {
  __shared__ __align__(16) float combL[NC];
  __shared__ float red[16][2];
  __shared__ float stat[2];
  const int m = blockIdx.x, tid = threadIdx.x;

  f32x4 cv = *(const f32x4*)(comb + (size_t)m * NC + tid * 4);
  *(f32x4*)(combL + tid * 4) = cv;
  float s  = cv[0] + cv[1] + cv[2] + cv[3];
  float ss = cv[0] * cv[0] + cv[1] * cv[1] + cv[2] * cv[2] + cv[3] * cv[3];
#pragma unroll
  for (int off = 1; off < 64; off <<= 1) {
    s  += __shfl_xor(s, off);
    ss += __shfl_xor(ss, off);
  }
  const int wid = tid >> 6;
  if ((tid & 63) == 0) { red[wid][0] = s; red[wid][1] = ss; }
  __syncthreads();
  if (tid == 0) {
    float s2 = 0.f, ss2 = 0.f;
#pragma unroll
    for (int i = 0; i < 16; ++i) { s2 += red[i][0]; ss2 += red[i][1]; }
    const float mean = s2 * (1.f / NC);
    const float var  = ss2 * (1.f / NC) - mean * mean;
    stat[0] = mean;
    stat[1] = rsqrtf(var + LN_EPS);
  }
  __syncthreads();
  const float mean = stat[0], rs = stat[1];
  const int j = tid;
  const float iv = (combL[j]          - mean) * rs * gamma[j]          + beta[j];
  const float fv = (combL[NO + j]     - mean) * rs * gamma[NO + j]     + beta[NO + j];
  const float gv = (combL[2 * NO + j] - mean) * rs * gamma[2 * NO + j] + beta[2 * NO + j];
  const float ov = (combL[3 * NO + j] - mean) * rs * gamma[3 * NO + j] + beta[3 * NO + j];
  const float cold = cst[(size_t)m * NO + j];
  const float cc = sigf(fv) * cold + sigf(iv) * tanhfast(gv);
  const float hh = sigf(ov) * cc;
  cst[(size_t)m * NO + j] = cc;
  out[((size_t)m * NS + t) * NO + j] = hh;
  hfrag[hfrag_idx(m, j)] = __float2bfloat16(hh);
}

// ---------------- fallback (small ws): fp32 path ----------------

__launch_bounds__(256)
__global__ void step_gemm_f32(const float* __restrict__ x, const float* __restrict__ hf,
                              const float* __restrict__ W, const float* __restrict__ bias,
                              float* __restrict__ comb, int t) {
  const int blk = blockIdx.x;
  const int tid = threadIdx.x;
  const int n   = blk * 16 + (tid & 15);
  const int mlo = tid >> 4;
  float a0 = 0.f, a1 = 0.f;
  for (int k = 0; k < NI; ++k) {
    const float wv = W[(size_t)k * NC + n];
    a0 += x[((size_t)mlo * NS + t) * NI + k] * wv;
    a1 += x[((size_t)(mlo + 16) * NS + t) * NI + k] * wv;
  }
  for (int k = 0; k < NO; ++k) {
    const float wv = W[(size_t)(NI + k) * NC + n];
    a0 += hf[mlo * NO + k] * wv;
    a1 += hf[(mlo + 16) * NO + k] * wv;
  }
  comb[(size_t)mlo * NC + n] = a0 + bias[n];
  comb[(size_t)(mlo + 16) * NC + n] = a1 + bias[n];
}

__global__ __launch_bounds__(1024)
void step_update_row_f32(const float* __restrict__ comb,
                         const float* __restrict__ gamma,
                         const float* __restrict__ beta,
                         float* __restrict__ cst,
                         float* __restrict__ out,
                         float* __restrict__ hf,
                         int t) {
  __shared__ __align__(16) float combL[NC];
  __shared__ float red[16][2];
  __shared__ float stat[2];
  const int m = blockIdx.x, tid = threadIdx.x;
  f32x4 cv = *(const f32x4*)(comb + (size_t)m * NC + tid * 4);
  *(f32x4*)(combL + tid * 4) = cv;
  float s  = cv[0] + cv[1] + cv[2] + cv[3];
  float ss = cv[0] * cv[0] + cv[1] * cv[1] + cv[2] * cv[2] + cv[3] * cv[3];
#pragma unroll
  for (int off = 1; off < 64; off <<= 1) {
    s  += __shfl_xor(s, off);
    ss += __shfl_xor(ss, off);
  }
  const int wid = tid >> 6;
  if ((tid & 63) == 0) { red[wid][0] = s; red[wid][1] = ss; }
  __syncthreads();
  if (tid == 0) {
    float s2 = 0.f, ss2 = 0.f;
    for (int i = 0; i < 16; ++i) { s2 += red[i][0]; ss2 += red[i][1]; }
    const float mean = s2 * (1.f / NC);
    const float var  = ss2 * (1.f / NC) - mean * mean;
    stat[0] = mean;
    stat[1] = rsqrtf(var + LN_EPS);
  }
  __syncthreads();
  const float mean = stat[0], rs = stat[1];
  const int j = tid;
  const float iv = (combL[j]          - mean) * rs * gamma[j]          + beta[j];
  const float fv = (combL[NO + j]     - mean) * rs * gamma[NO + j]     + beta[NO + j];
  const float gv = (combL[2 * NO + j] - mean) * rs * gamma[2 * NO + j] + beta[2 * NO + j];
  const float ov = (combL[3 * NO + j] - mean) * rs * gamma[3 * NO + j] + beta[3 * NO + j];
  const float cold = cst[(size_t)m * NO + j];
  const float cc = sigf(fv) * cold + sigf(iv) * tanhfast(gv);
  const float hh = sigf(ov) * cc;
  cst[(size_t)m * NO + j] = cc;
  out[((size_t)m * NS + t) * NO + j] = hh;
  hf[(size_t)m * NO + j] = hh;
}

// ---------------- launch ----------------

extern "C" void kernel_launch(void* const* d_in, const int* in_sizes, int n_in,
                              void* d_out, int out_size, void* d_ws, size_t ws_size,
                              hipStream_t stream) {
  (void)in_sizes; (void)n_in; (void)out_size;
  const float* x     = (const float*)d_in[0];
  const float* W     = (const float*)d_in[1];
  const float* bias  = (const float*)d_in[2];
  const float* gamma = (const float*)d_in[3];
  const float* beta  = (const float*)d_in[4];
  const float* hx0   = (const float*)d_in[5];
  const float* cx0   = (const float*)d_in[6];
  float* outp = (float*)d_out;

  char* ws = (char*)d_ws;
  size_t off = 0;
  auto alloc = [&](size_t bytes) -> char* {
    off = (off + 255) & ~(size_t)255;
    char* p = ws + off;
    off += bytes;
    return p;
  };
  // small buffers first (fallback needs only these)
  float* comb          = (float*)alloc((size_t)NB * NC * 4);        // 512KB
  float* cst           = (float*)alloc((size_t)NB * NO * 4);        // 128KB
  float* hf            = (float*)alloc((size_t)NB * NO * 4);        // 128KB
  __hip_bfloat16* hfrag = (__hip_bfloat16*)alloc((size_t)NB * NO * 2);  // 64KB
  // big buffers
  __hip_bfloat16* xfrag = (__hip_bfloat16*)alloc((size_t)NB * NS * NI * 2);  // 16.8MB
  __hip_bfloat16* WF    = (__hip_bfloat16*)alloc((size_t)NK * NC * 2);       // 16.8MB
  const bool big = (ws_size >= off);   // ws_size constant -> same path every call

  hipLaunchKernelGGL(init_state, dim3((NB * NO) / 256), dim3(256), 0, stream,
                     hx0, cx0, hfrag, cst, hf);
  if (big) {
    hipLaunchKernelGGL(pack_x, dim3(NS, 32), dim3(128), 0, stream, x, xfrag);
    hipLaunchKernelGGL(pack_wf, dim3(256 * 64), dim3(64), 0, stream, W, WF);
    for (int t = 0; t < NS; ++t) {
      hipLaunchKernelGGL(step_gemm_mfma, dim3(256), dim3(512), 0, stream,
                         xfrag, hfrag, WF, bias, comb, t);
      hipLaunchKernelGGL(step_update_row, dim3(NB), dim3(1024), 0, stream,
                         comb, gamma, beta, cst, outp, hfrag, t);
    }
  } else {
    for (int t = 0; t < NS; ++t) {
      hipLaunchKernelGGL(step_gemm_f32, dim3(256), dim3(256), 0, stream,
                         x, hf, W, bias, comb, t);
      hipLaunchKernelGGL(step_update_row_f32, dim3(NB), dim3(1024), 0, stream,
                         comb, gamma, beta, cst, outp, hf, t);
    }
  }
}